// Round 4
// baseline (4998.008 us; speedup 1.0000x reference)
//
#include <hip/hip_runtime.h>

typedef unsigned short u16;
typedef __attribute__((ext_vector_type(8))) short short8;
typedef __attribute__((ext_vector_type(4))) unsigned short us4;
typedef __attribute__((ext_vector_type(4))) float f32x4;

constexpr int HID = 2048;
constexpr int CD  = 8192;   // conv dim (q|k|v channels)
constexpr int KD  = 2048;   // key dim
constexpr int VD  = 4096;   // value dim
constexpr int NKH = 16;
constexpr int NVH = 32;
constexpr int DH  = 128;
constexpr int CH  = 64;     // chunk
constexpr int NB  = 2;      // batch
constexpr int SL  = 4096;   // seq
constexpr int NTOK = NB * SL;       // 8192
constexpr int TSEG = 8;             // time segments
constexpr int SLS  = SL / TSEG;     // 512 tokens per batch per segment
constexpr int NCS  = SLS / CH;      // 8 chunks per (b,h) per segment
constexpr int MSEG = NB * SLS;      // 1024 rows per segment GEMM

__device__ __forceinline__ float b2f(u16 u){
  unsigned v = ((unsigned)u) << 16;
  return __builtin_bit_cast(float, v);
}
__device__ __forceinline__ u16 f2b(float f){
  unsigned u = __builtin_bit_cast(unsigned, f);
  u = (u + 0x7fffu + ((u >> 16) & 1u)) >> 16;
  return (u16)u;
}
__device__ __forceinline__ short8 ld8(const u16* p){ return *(const short8*)p; }
__device__ __forceinline__ float siluf(float x){ return x / (1.f + __expf(-x)); }

__global__ void k_probe(float* out, float v){ out[0] = v; }

// ---- GEMM: C[M][N] = A[M][K] @ B[K][N], B is f32 row-major, A f32 or bf16 ----
// SEG=1: A rows come from x at (b*SL + seg_base + local), C rows compact [MSEG].
template<int AF32, int OBF, int SEG>
__global__ __launch_bounds__(256, 2) void k_gemm(const void* __restrict__ Ap,
    const float* __restrict__ B, void* __restrict__ Cp, int K, int N, int seg_base){
  __shared__ __align__(16) u16 As[128 * 32];
  __shared__ __align__(16) u16 Bs[128 * 32];
  const int tid = threadIdx.x;
  const int l = tid & 63, w = tid >> 6;
  const int wr = w >> 1, wc = w & 1;
  const int gy = blockIdx.y;
  long arow0, crow0;
  if (SEG){ long b = gy >> 2; arow0 = b * SL + seg_base + ((gy & 3) << 7); crow0 = (long)gy << 7; }
  else    { arow0 = crow0 = (long)gy << 7; }
  const long n0 = (long)blockIdx.x * 128;
  const int r0s = tid >> 2, c0s = (tid & 3) * 8, r1s = r0s + 64;
  const int kb0 = tid >> 4, kb1 = kb0 + 16, bn0 = (tid & 15) * 8;
  f32x4 acc[4][4] = {};
  const int NK = K >> 5;
  const float* Af = (const float*)Ap;
  const u16*  Ab = (const u16*)Ap;
  f32x4 fa0, fa0b, fa1, fa1b;
  short8 ra0, ra1;
  if (AF32){
    fa0  = *(const f32x4*)(Af + (arow0 + r0s) * (long)K + c0s);
    fa0b = *(const f32x4*)(Af + (arow0 + r0s) * (long)K + c0s + 4);
    fa1  = *(const f32x4*)(Af + (arow0 + r1s) * (long)K + c0s);
    fa1b = *(const f32x4*)(Af + (arow0 + r1s) * (long)K + c0s + 4);
  } else {
    ra0 = ld8(Ab + (arow0 + r0s) * (long)K + c0s);
    ra1 = ld8(Ab + (arow0 + r1s) * (long)K + c0s);
  }
  f32x4 fb0  = *(const f32x4*)(B + (long)kb0 * N + n0 + bn0);
  f32x4 fb0b = *(const f32x4*)(B + (long)kb0 * N + n0 + bn0 + 4);
  f32x4 fb1  = *(const f32x4*)(B + (long)kb1 * N + n0 + bn0);
  f32x4 fb1b = *(const f32x4*)(B + (long)kb1 * N + n0 + bn0 + 4);
  for (int kt = 0; kt < NK; ++kt){
    __syncthreads();
    if (AF32){
      short8 s0, s1;
      #pragma unroll
      for (int e = 0; e < 4; e++){
        s0[e] = (short)f2b(fa0[e]);  s0[4+e] = (short)f2b(fa0b[e]);
        s1[e] = (short)f2b(fa1[e]);  s1[4+e] = (short)f2b(fa1b[e]);
      }
      *(short8*)&As[r0s*32 + c0s] = s0;
      *(short8*)&As[r1s*32 + c0s] = s1;
    } else {
      *(short8*)&As[r0s*32 + c0s] = ra0;
      *(short8*)&As[r1s*32 + c0s] = ra1;
    }
    #pragma unroll
    for (int e = 0; e < 4; e++){
      Bs[(bn0+e)*32 + kb0]   = f2b(fb0[e]);
      Bs[(bn0+4+e)*32 + kb0] = f2b(fb0b[e]);
      Bs[(bn0+e)*32 + kb1]   = f2b(fb1[e]);
      Bs[(bn0+4+e)*32 + kb1] = f2b(fb1b[e]);
    }
    __syncthreads();
    if (kt + 1 < NK){
      const int kk = (kt + 1) * 32;
      if (AF32){
        fa0  = *(const f32x4*)(Af + (arow0 + r0s) * (long)K + kk + c0s);
        fa0b = *(const f32x4*)(Af + (arow0 + r0s) * (long)K + kk + c0s + 4);
        fa1  = *(const f32x4*)(Af + (arow0 + r1s) * (long)K + kk + c0s);
        fa1b = *(const f32x4*)(Af + (arow0 + r1s) * (long)K + kk + c0s + 4);
      } else {
        ra0 = ld8(Ab + (arow0 + r0s) * (long)K + kk + c0s);
        ra1 = ld8(Ab + (arow0 + r1s) * (long)K + kk + c0s);
      }
      fb0  = *(const f32x4*)(B + (long)(kk + kb0) * N + n0 + bn0);
      fb0b = *(const f32x4*)(B + (long)(kk + kb0) * N + n0 + bn0 + 4);
      fb1  = *(const f32x4*)(B + (long)(kk + kb1) * N + n0 + bn0);
      fb1b = *(const f32x4*)(B + (long)(kk + kb1) * N + n0 + bn0 + 4);
    }
    short8 af[4], bf[4];
    const int lr = l & 15, lk = (l >> 4) * 8;
    #pragma unroll
    for (int mi = 0; mi < 4; mi++) af[mi] = *(const short8*)&As[(wr*64 + mi*16 + lr)*32 + lk];
    #pragma unroll
    for (int ni = 0; ni < 4; ni++) bf[ni] = *(const short8*)&Bs[(wc*64 + ni*16 + lr)*32 + lk];
    #pragma unroll
    for (int mi = 0; mi < 4; mi++)
      #pragma unroll
      for (int ni = 0; ni < 4; ni++)
        acc[mi][ni] = __builtin_amdgcn_mfma_f32_16x16x32_bf16(af[mi], bf[ni], acc[mi][ni], 0, 0, 0);
  }
  const int lr = l & 15, lg = l >> 4;
  #pragma unroll
  for (int mi = 0; mi < 4; mi++)
    #pragma unroll
    for (int ni = 0; ni < 4; ni++){
      long row = crow0 + wr*64 + mi*16 + lg*4;
      long col = n0 + wc*64 + ni*16 + lr;
      #pragma unroll
      for (int r = 0; r < 4; r++){
        if (OBF) ((u16*)Cp)[(row + r) * N + col] = f2b(acc[mi][ni][r]);
        else     ((float*)Cp)[(row + r) * N + col] = acc[mi][ni][r];
      }
    }
}

// ---- beta = sigmoid(x@w_b), g = -exp(a_log)*softplus(x@w_a + dt_bias) ----
__global__ __launch_bounds__(256) void k_beta_g(const float* __restrict__ x,
    const float* __restrict__ wb, const float* __restrict__ wa,
    const float* __restrict__ dtb, const float* __restrict__ alog,
    float* __restrict__ beta, float* __restrict__ g){
  __shared__ float xs[HID];
  __shared__ float red[64][4];
  long tok = blockIdx.x;
  int t = threadIdx.x;
  #pragma unroll
  for (int u = 0; u < 8; u++) xs[u*256 + t] = x[tok * HID + u*256 + t];
  __syncthreads();
  int hh = t & 63, ks = t >> 6;
  const float* wcol = (hh < 32) ? wb : wa;
  int h = hh & 31;
  float s = 0.f;
  for (int k = ks*512; k < ks*512 + 512; ++k) s += xs[k] * wcol[k*32 + h];
  red[hh][ks] = s;
  __syncthreads();
  if (ks == 0){
    float v = red[hh][0] + red[hh][1] + red[hh][2] + red[hh][3];
    if (hh < 32){
      beta[tok*NVH + h] = 1.f / (1.f + expf(-v));
    } else {
      float a = v + dtb[h];
      float sp = fmaxf(a, 0.f) + log1pf(expf(-fabsf(a)));
      g[tok*NVH + h] = -expf(alog[h]) * sp;
    }
  }
}

// ---- save last 3 pre-conv rows of this segment (history for next segment) ----
__global__ void k_halo(const u16* __restrict__ qkvs, u16* __restrict__ halo){
  int c = blockIdx.x * 256 + threadIdx.x;
  int r = blockIdx.y;            // 0..2
  int b = blockIdx.z;
  halo[((long)b * 3 + r) * CD + c] = qkvs[((long)b * SLS + SLS - 3 + r) * CD + c];
}

// ---- causal depthwise conv1d(4) + silu, in place over segment ----
__global__ void k_conv(u16* __restrict__ qkvs, const float* __restrict__ cw,
                       const u16* __restrict__ halo_prev, int first){
  int c = blockIdx.x * 256 + threadIdx.x;
  int b = blockIdx.z;
  float w0 = cw[c*4+0], w1 = cw[c*4+1], w2 = cw[c*4+2], w3 = cw[c*4+3];
  u16* base = qkvs + (long)b * SLS * CD + c;
  float h0 = 0.f, h1 = 0.f, h2 = 0.f;
  if (!first){
    const u16* hp = halo_prev + (long)b * 3 * CD + c;
    h0 = b2f(hp[0]); h1 = b2f(hp[CD]); h2 = b2f(hp[2*CD]);
  }
  for (int s = 0; s < SLS; ++s){
    float xv = b2f(base[(long)s * CD]);
    float y = w0*h0 + w1*h1 + w2*h2 + w3*xv;
    base[(long)s * CD] = f2b(siluf(y));
    h0 = h1; h1 = h2; h2 = xv;
  }
}

// ---- per-chunk prep (+ fused q l2norm): kn, qn, gc, X=(I-A)^-1, v_c, k_cumdecay ----
__global__ __launch_bounds__(256, 2) void k_prep(const u16* __restrict__ qkvs,
    const float* __restrict__ beta, const float* __restrict__ g,
    u16* __restrict__ knG, u16* __restrict__ qnG, u16* __restrict__ vcG,
    u16* __restrict__ kcdG, float* __restrict__ gcG, int seg_base){
  __shared__ __align__(16) u16 kn_s[64][136];
  __shared__ __align__(16) u16 vb_s[64][136];
  __shared__ float Xm[64][65];
  __shared__ float gch[64], bet[64], bej[64];
  int id = blockIdx.x;
  int n = id & (NCS-1), h = (id >> 3) & 31;
  long b = id >> 8;
  int kh = h >> 1;
  int t = threadIdx.x;
  long mb = b * SLS + n * CH;              // seg-local row base
  long tokb = b * SL + seg_base + n * CH;  // global token base

  if (t < 64) bet[t] = beta[(tokb + t) * NVH + h];
  if (t >= 64 && t < 128){
    int i = t - 64;
    float gv = g[(tokb + i) * NVH + h];
    #pragma unroll
    for (int off = 1; off < 64; off <<= 1){
      float nv = __shfl_up(gv, off);
      if (i >= off) gv += nv;
    }
    gch[i] = gv;
    gcG[(b * NVH + h) * (long)SLS + n * CH + i] = gv;
  }
  int row = t >> 2, qq = t & 3;
  long kqbase = ((b * NKH + kh) * (long)SLS + n * CH + row) * DH + qq * 32;
  // ---- q: l2norm * K^-0.5 ----
  {
    const u16* qp = qkvs + (mb + row) * (long)CD + kh * DH + qq * 32;
    short8 qr[4];
    #pragma unroll
    for (int u = 0; u < 4; u++) qr[u] = ld8(qp + u * 8);
    float sqq = 0.f;
    #pragma unroll
    for (int u = 0; u < 4; u++)
      #pragma unroll
      for (int e = 0; e < 8; e++){ float v = b2f((u16)qr[u][e]); sqq += v * v; }
    sqq += __shfl_xor(sqq, 1); sqq += __shfl_xor(sqq, 2);
    float qsc = rsqrtf(sqq + 1e-6f) * 0.08838834764831845f;
    if ((h & 1) == 0){
      #pragma unroll
      for (int u = 0; u < 4; u++){
        short8 o;
        #pragma unroll
        for (int e = 0; e < 8; e++) o[e] = (short)f2b(b2f((u16)qr[u][e]) * qsc);
        *(short8*)(qnG + kqbase + u*8) = o;
      }
    }
  }
  // ---- k: l2norm; v: raw ----
  const u16* kp = qkvs + (mb + row) * (long)CD + KD + kh * DH + qq * 32;
  short8 kr[4];
  #pragma unroll
  for (int u = 0; u < 4; u++) kr[u] = ld8(kp + u * 8);
  float kf[32];
  float sq = 0.f;
  #pragma unroll
  for (int u = 0; u < 4; u++)
    #pragma unroll
    for (int e = 0; e < 8; e++){
      float v = b2f((u16)kr[u][e]); kf[u*8+e] = v; sq += v * v;
    }
  sq += __shfl_xor(sq, 1); sq += __shfl_xor(sq, 2);
  float ksc = rsqrtf(sq + 1e-6f);
  const u16* vp = qkvs + (mb + row) * (long)CD + 2*KD + h * DH + qq * 32;
  short8 vr[4];
  #pragma unroll
  for (int u = 0; u < 4; u++) vr[u] = ld8(vp + u * 8);
  __syncthreads();   // S1: bet, gch ready
  {
    float bt = bet[row];
    #pragma unroll
    for (int u = 0; u < 4; u++){
      short8 o, ov;
      #pragma unroll
      for (int e = 0; e < 8; e++){
        o[e]  = (short)f2b(kf[u*8+e] * ksc);
        ov[e] = (short)f2b(b2f((u16)vr[u][e]) * bt);
      }
      *(short8*)&kn_s[row][qq*32 + u*8] = o;
      if ((h & 1) == 0) *(short8*)(knG + kqbase + u*8) = o;
      *(short8*)&vb_s[row][qq*32 + u*8] = ov;
    }
    if (t < 64) bej[t] = bet[t] * __expf(gch[t]);
  }
  __syncthreads();   // S2: kn_s, vb_s, bej ready
  {
    int ti = (t >> 4) * 4, tj = (t & 15) * 4;
    float dot[4][4] = {};
    for (int c = 0; c < 128; c++){
      float av[4], bv[4];
      #pragma unroll
      for (int r = 0; r < 4; r++) av[r] = b2f(kn_s[ti + r][c]);
      #pragma unroll
      for (int s2 = 0; s2 < 4; s2++) bv[s2] = b2f(kn_s[tj + s2][c]);
      #pragma unroll
      for (int r = 0; r < 4; r++)
        #pragma unroll
        for (int s2 = 0; s2 < 4; s2++) dot[r][s2] += av[r] * bv[s2];
    }
    #pragma unroll
    for (int r = 0; r < 4; r++)
      #pragma unroll
      for (int s2 = 0; s2 < 4; s2++){
        int i = ti + r, j = tj + s2;
        float v = 0.f;
        if (i == j) v = 1.f;
        else if (j < i) v = -bet[i] * __expf(gch[i] - gch[j]) * dot[r][s2];
        Xm[i][j] = v;
      }
  }
  __syncthreads();   // S3: Xm init done
  {
    int j = t & 63, wv = t >> 6;
    for (int m = 1; m < 63; ++m){
      if (j < m){
        float xmj = Xm[m][j];
        for (int i = m + 1 + wv; i < 64; i += 4)
          Xm[i][j] += Xm[i][m] * xmj;
      }
      __syncthreads();
    }
  }
  __syncthreads();
  {
    int i0 = (t >> 4) * 4, c0 = (t & 15) * 8;
    float ak[4][8] = {}, av[4][8] = {};
    for (int jj = 0; jj < 64; ++jj){
      float xr[4], w1[4];
      #pragma unroll
      for (int r = 0; r < 4; r++){ xr[r] = Xm[i0 + r][jj]; w1[r] = xr[r] * bej[jj]; }
      float kv[8], vv[8];
      #pragma unroll
      for (int e = 0; e < 8; e++){ kv[e] = b2f(kn_s[jj][c0 + e]); vv[e] = b2f(vb_s[jj][c0 + e]); }
      #pragma unroll
      for (int r = 0; r < 4; r++)
        #pragma unroll
        for (int e = 0; e < 8; e++){ ak[r][e] += w1[r] * kv[e]; av[r][e] += xr[r] * vv[e]; }
    }
    long cb = ((b * NVH + h) * (long)NCS + n) * CH;
    #pragma unroll
    for (int r = 0; r < 4; r++){
      short8 o1, o2;
      #pragma unroll
      for (int e = 0; e < 8; e++){ o1[e] = (short)f2b(ak[r][e]); o2[e] = (short)f2b(av[r][e]); }
      *(short8*)(kcdG + (cb + i0 + r) * DH + c0) = o1;
      *(short8*)(vcG  + (cb + i0 + r) * DH + c0) = o2;
    }
  }
}

// ---- qk attention with decay (inclusive-lower) ----
__global__ __launch_bounds__(256, 2) void k_qkattn(const u16* __restrict__ qnG,
    const u16* __restrict__ knG, const float* __restrict__ gcG, u16* __restrict__ attnG){
  __shared__ __align__(16) u16 qs[64][136], ks[64][136];
  __shared__ float gch[64];
  int id = blockIdx.x;
  int n = id & (NCS-1), h = (id >> 3) & 31;
  long b = id >> 8;
  int kh = h >> 1;
  int t = threadIdx.x;
  int row = t >> 2, qq = t & 3;
  long kqbase = ((b * NKH + kh) * (long)SLS + n * CH + row) * DH + qq * 32;
  #pragma unroll
  for (int u = 0; u < 4; u++){
    *(short8*)&qs[row][qq*32 + u*8] = ld8(qnG + kqbase + u*8);
    *(short8*)&ks[row][qq*32 + u*8] = ld8(knG + kqbase + u*8);
  }
  if (t < 64) gch[t] = gcG[(b * NVH + h) * (long)SLS + n * CH + t];
  __syncthreads();
  int ti = (t >> 4) * 4, tj = (t & 15) * 4;
  float dot[4][4] = {};
  for (int c = 0; c < 128; c++){
    float av[4], bv[4];
    #pragma unroll
    for (int r = 0; r < 4; r++) av[r] = b2f(qs[ti + r][c]);
    #pragma unroll
    for (int s2 = 0; s2 < 4; s2++) bv[s2] = b2f(ks[tj + s2][c]);
    #pragma unroll
    for (int r = 0; r < 4; r++)
      #pragma unroll
      for (int s2 = 0; s2 < 4; s2++) dot[r][s2] += av[r] * bv[s2];
  }
  long cb = ((b * NVH + h) * (long)NCS + n) * CH;
  #pragma unroll
  for (int r = 0; r < 4; r++){
    int i = ti + r;
    us4 o;
    #pragma unroll
    for (int s2 = 0; s2 < 4; s2++){
      int j = tj + s2;
      float v = (j <= i) ? dot[r][s2] * __expf(gch[i] - gch[j]) : 0.f;
      o[s2] = f2b(v);
    }
    *(us4*)(attnG + (cb + i) * CH + tj) = o;
  }
}

// ---- sequential scan over this segment's chunks; V sliced by 16; state in global ----
__global__ __launch_bounds__(256, 2) void k_scan(const u16* __restrict__ qnG,
    const u16* __restrict__ knG, const u16* __restrict__ vcG, const u16* __restrict__ kcdG,
    const u16* __restrict__ attnG, const float* __restrict__ gcG, u16* __restrict__ core,
    float* __restrict__ stateG, int seg_base, int first){
  __shared__ __align__(16) float st[128][16];
  __shared__ __align__(16) u16 kcd_s[64][136], kn_s[64][136], qn_s[64][136];
  __shared__ __align__(16) u16 at_s[64][72];
  __shared__ __align__(16) u16 vc_s[64][16];
  __shared__ __align__(16) float vn[64][16];
  __shared__ float e1[64], e2[64], gch[64];
  __shared__ float eglS;
  int id = blockIdx.x;
  int bh = id & 63, vs = id >> 6;
  int h = bh & 31;
  long b = bh >> 5;
  int kh = h >> 1, VB0 = vs * 16;
  int t = threadIdx.x;
  {
    int c = t >> 1, half = t & 1, sw = (c >> 5) & 3;
    if (first){
      f32x4 z = {0.f, 0.f, 0.f, 0.f};
      *(f32x4*)&st[c][4 * ((half*2)     ^ sw)] = z;
      *(f32x4*)&st[c][4 * ((half*2 + 1) ^ sw)] = z;
    } else {
      const float* sp = stateG + ((long)bh * 128 + c) * 128 + VB0 + half * 8;
      *(f32x4*)&st[c][4 * ((half*2)     ^ sw)] = *(const f32x4*)(sp);
      *(f32x4*)&st[c][4 * ((half*2 + 1) ^ sw)] = *(const f32x4*)(sp + 4);
    }
  }
  int i4 = t >> 2, s4 = t & 3;
  int cD = t >> 1, hf = t & 1;
  long hb = bh;
  long khb = b * NKH + kh;

  for (int n = 0; n < NCS; ++n){
    __syncthreads();
    {
      int row = t >> 2, qq = t & 3;
      long cbase = ((hb * NCS + n) * CH + row) * (long)DH;
      const u16* kcp = kcdG + cbase + qq * 32;
      #pragma unroll
      for (int u = 0; u < 4; u++) *(short8*)&kcd_s[row][qq*32 + u*8] = ld8(kcp + u*8);
      long knb = (khb * SLS + n * CH + row) * (long)DH;
      const u16* knp = knG + knb + qq * 32;
      #pragma unroll
      for (int u = 0; u < 4; u++) *(short8*)&kn_s[row][qq*32 + u*8] = ld8(knp + u*8);
      const u16* qnp = qnG + knb + qq * 32;
      #pragma unroll
      for (int u = 0; u < 4; u++) *(short8*)&qn_s[row][qq*32 + u*8] = ld8(qnp + u*8);
      const u16* atp = attnG + (hb * NCS + n) * (long)(CH * CH) + row * CH + qq * 16;
      *(short8*)&at_s[row][qq*16]     = ld8(atp);
      *(short8*)&at_s[row][qq*16 + 8] = ld8(atp + 8);
      if (t < 64){
        const u16* vcp = vcG + ((hb * NCS + n) * CH + t) * (long)DH + VB0;
        *(short8*)&vc_s[t][0] = ld8(vcp);
        *(short8*)&vc_s[t][8] = ld8(vcp + 8);
        gch[t] = gcG[hb * SLS + n * CH + t];
      }
    }
    __syncthreads();
    if (t < 64){
      e1[t] = __expf(gch[t]);
      e2[t] = __expf(gch[63] - gch[t]);
      if (t == 0) eglS = __expf(gch[63]);
    }
    // phase A: v_new = v_c - kcd @ state
    {
      float acc[16] = {};
      for (int cc = 0; cc < 32; ++cc){
        int c = s4 * 32 + cc;
        float kv = b2f(kcd_s[i4][c]);
        int sw = (c >> 5) & 3;
        #pragma unroll
        for (int u = 0; u < 4; ++u){
          f32x4 sv = *(const f32x4*)&st[c][4 * (u ^ sw)];
          #pragma unroll
          for (int e = 0; e < 4; e++) acc[u*4 + e] += kv * sv[e];
        }
      }
      #pragma unroll
      for (int e = 0; e < 16; e++){
        acc[e] += __shfl_xor(acc[e], 1);
        acc[e] += __shfl_xor(acc[e], 2);
      }
      int swv = (i4 >> 4) & 3;
      #pragma unroll
      for (int u = 0; u < 4; u++){
        if (u == s4){
          f32x4 vnv;
          #pragma unroll
          for (int e = 0; e < 4; e++) vnv[e] = b2f(vc_s[i4][u*4 + e]) - acc[u*4 + e];
          *(f32x4*)&vn[i4][4 * (u ^ swv)] = vnv;
        }
      }
    }
    __syncthreads();
    // phase B + C: o = e1*q@state + attn@v_new
    {
      float acc[16] = {}, acc3[16] = {};
      for (int cc = 0; cc < 32; ++cc){
        int c = s4 * 32 + cc;
        float qv = b2f(qn_s[i4][c]);
        int sw = (c >> 5) & 3;
        #pragma unroll
        for (int u = 0; u < 4; ++u){
          f32x4 sv = *(const f32x4*)&st[c][4 * (u ^ sw)];
          #pragma unroll
          for (int e = 0; e < 4; e++) acc[u*4 + e] += qv * sv[e];
        }
      }
      for (int jj = 0; jj < 16; ++jj){
        int j = s4 * 16 + jj;
        float av = b2f(at_s[i4][j]);
        int swv = (j >> 4) & 3;
        #pragma unroll
        for (int u = 0; u < 4; ++u){
          f32x4 vv = *(const f32x4*)&vn[j][4 * (u ^ swv)];
          #pragma unroll
          for (int e = 0; e < 4; e++) acc3[u*4 + e] += av * vv[e];
        }
      }
      float e1i = e1[i4];
      #pragma unroll
      for (int e = 0; e < 16; e++){
        float v = e1i * acc[e] + acc3[e];
        v += __shfl_xor(v, 1);
        v += __shfl_xor(v, 2);
        acc[e] = v;
      }
      if (s4 == 0){
        long orow = ((long)b * SL + seg_base + n * CH + i4) * VD + h * DH + VB0;
        short8 o1, o2;
        #pragma unroll
        for (int e = 0; e < 8; e++){ o1[e] = (short)f2b(acc[e]); o2[e] = (short)f2b(acc[8 + e]); }
        *(short8*)(core + orow)     = o1;
        *(short8*)(core + orow + 8) = o2;
      }
    }
    __syncthreads();
    // phase D: state = state*exp(gl) + (k*exp(gl-g))^T @ v_new
    {
      float egl = eglS;
      int swD = (cD >> 5) & 3;
      f32x4 s0v = *(const f32x4*)&st[cD][4 * ((hf*2)     ^ swD)];
      f32x4 s1v = *(const f32x4*)&st[cD][4 * ((hf*2 + 1) ^ swD)];
      float sacc[8];
      #pragma unroll
      for (int e = 0; e < 4; e++){ sacc[e] = s0v[e] * egl; sacc[4+e] = s1v[e] * egl; }
      for (int i = 0; i < 64; ++i){
        float kv = b2f(kn_s[i][cD]) * e2[i];
        int swv = (i >> 4) & 3;
        f32x4 v0 = *(const f32x4*)&vn[i][4 * ((hf*2)     ^ swv)];
        f32x4 v1 = *(const f32x4*)&vn[i][4 * ((hf*2 + 1) ^ swv)];
        #pragma unroll
        for (int e = 0; e < 4; e++){ sacc[e] += kv * v0[e]; sacc[4+e] += kv * v1[e]; }
      }
      f32x4 o0, o1;
      #pragma unroll
      for (int e = 0; e < 4; e++){ o0[e] = sacc[e]; o1[e] = sacc[4+e]; }
      *(f32x4*)&st[cD][4 * ((hf*2)     ^ swD)] = o0;
      *(f32x4*)&st[cD][4 * ((hf*2 + 1) ^ swD)] = o1;
    }
  }
  __syncthreads();
  {
    int c = t >> 1, half = t & 1, sw = (c >> 5) & 3;
    float* sp = stateG + ((long)bh * 128 + c) * 128 + VB0 + half * 8;
    *(f32x4*)(sp)     = *(const f32x4*)&st[c][4 * ((half*2)     ^ sw)];
    *(f32x4*)(sp + 4) = *(const f32x4*)&st[c][4 * ((half*2 + 1) ^ sw)];
  }
}

// ---- RMSNorm(core)*norm_w*silu(z) -> gated (in place over core) ----
__global__ void k_gate(u16* __restrict__ core, const u16* __restrict__ zb,
                       const float* __restrict__ nw){
  long wid = (long)blockIdx.x * 4 + (threadIdx.x >> 6);
  int l = threadIdx.x & 63;
  long base = wid * DH + l * 2;
  float v0 = b2f(core[base]), v1 = b2f(core[base + 1]);
  float sq = v0*v0 + v1*v1;
  #pragma unroll
  for (int off = 1; off < 64; off <<= 1) sq += __shfl_xor(sq, off);
  float sc = rsqrtf(sq * (1.f / 128.f) + 1e-6f);
  float z0 = b2f(zb[base]), z1 = b2f(zb[base + 1]);
  core[base]     = f2b(v0 * sc * nw[l*2]     * siluf(z0));
  core[base + 1] = f2b(v1 * sc * nw[l*2 + 1] * siluf(z1));
}

// ---- launch ----
// Workspace (bytes), total 119,996,416 (~114.4 MB):
//   [0,         67108864)  core bf16 [NTOK][VD] (gated in place)
//   [67108864,  83886080)  qkv_seg bf16 [MSEG][CD] (conv in place)
//   [83886080,  88080384)  qn_seg   [NB*NKH][SLS][DH]
//   [88080384,  92274688)  kn_seg
//   [92274688, 100663296)  vc_seg   [NB*NVH][NCS][CH][DH]
//   [100663296,109051904)  kcd_seg
//   [109051904,113246208)  attn_seg [NB*NVH][NCS][CH][CH]
//   [113246208,117440512)  state f32 [NB*NVH][128][128]
//   [117440512,118489088)  beta f32 [NTOK][NVH]
//   [118489088,119537664)  g    f32 [NTOK][NVH]
//   [119537664,119799808)  gc_seg f32 [NB*NVH][SLS]
//   [119799808,119996416)  halo x2 (pre-conv 3-row checkpoints)
//   z bf16 [NTOK][VD] lives in d_out (dead before final GEMM writes it)
extern "C" void kernel_launch(void* const* d_in, const int* in_sizes, int n_in,
                              void* d_out, int out_size, void* d_ws, size_t ws_size,
                              hipStream_t stream) {
  const float* x      = (const float*)d_in[0];
  const float* w_qkv  = (const float*)d_in[1];
  const float* w_z    = (const float*)d_in[2];
  const float* w_b    = (const float*)d_in[3];
  const float* w_a    = (const float*)d_in[4];
  const float* conv_w = (const float*)d_in[5];
  const float* dt_b   = (const float*)d_in[6];
  const float* a_log  = (const float*)d_in[7];
  const float* norm_w = (const float*)d_in[8];
  const float* w_out  = (const float*)d_in[9];
  float* out = (float*)d_out;

  if (ws_size < 119996416ul){
    k_probe<<<dim3(1), dim3(1), 0, stream>>>(out, (float)(ws_size >> 20));
    return;
  }

  char* W = (char*)d_ws;
  u16*   coreb  = (u16*)(W + 0l);
  u16*   qkvs   = (u16*)(W + 67108864l);
  u16*   qnb    = (u16*)(W + 83886080l);
  u16*   knb    = (u16*)(W + 88080384l);
  u16*   vcb    = (u16*)(W + 92274688l);
  u16*   kcdb   = (u16*)(W + 100663296l);
  u16*   attnb  = (u16*)(W + 109051904l);
  float* stateb = (float*)(W + 113246208l);
  float* betab  = (float*)(W + 117440512l);
  float* gb     = (float*)(W + 118489088l);
  float* gcb    = (float*)(W + 119537664l);
  u16*   halo0  = (u16*)(W + 119799808l);
  u16*   halo1  = (u16*)(W + 119898112l);
  u16*   zb     = (u16*)d_out;   // dead before final GEMM writes out

  k_beta_g<<<dim3(NTOK), dim3(256), 0, stream>>>(x, w_b, w_a, dt_b, a_log, betab, gb);
  for (int seg = 0; seg < TSEG; ++seg){
    int sb = seg * SLS;
    u16* hcur  = (seg & 1) ? halo1 : halo0;
    u16* hprev = (seg & 1) ? halo0 : halo1;
    k_gemm<1,1,1><<<dim3(CD/128, MSEG/128), dim3(256), 0, stream>>>(x, w_qkv, qkvs, HID, CD, sb);
    k_halo<<<dim3(CD/256, 3, NB), dim3(256), 0, stream>>>(qkvs, hcur);
    k_conv<<<dim3(CD/256, 1, NB), dim3(256), 0, stream>>>(qkvs, conv_w, hprev, seg == 0);
    k_prep<<<dim3(NB*NVH*NCS), dim3(256), 0, stream>>>(qkvs, betab, gb, knb, qnb, vcb, kcdb, gcb, sb);
    k_qkattn<<<dim3(NB*NVH*NCS), dim3(256), 0, stream>>>(qnb, knb, gcb, attnb);
    k_scan<<<dim3(NB*NVH*8), dim3(256), 0, stream>>>(qnb, knb, vcb, kcdb, attnb, gcb,
                                                     coreb, stateb, sb, seg == 0);
  }
  k_gemm<1,1,0><<<dim3(VD/128, NTOK/128), dim3(256), 0, stream>>>(x, w_z, zb, HID, VD, 0);
  k_gate<<<dim3(NTOK*NVH/4), dim3(256), 0, stream>>>(coreb, zb, norm_w);
  k_gemm<0,0,0><<<dim3(HID/128, NTOK/128), dim3(256), 0, stream>>>(coreb, w_out, out, VD, HID, 0);
}